// Round 1
// baseline (450.435 us; speedup 1.0000x reference)
//
#include <hip/hip_runtime.h>
#include <stdint.h>

#define NN 8192
#define FF 256
#define HH 64

typedef __attribute__((ext_vector_type(8))) short bf16x8;
typedef __attribute__((ext_vector_type(4))) float f32x4;

__device__ __forceinline__ uint16_t f2bf(float f) {
  union { float f; uint32_t i; } c; c.f = f;
  uint32_t r = c.i + 0x7FFFu + ((c.i >> 16) & 1u);
  return (uint16_t)(r >> 16);
}

// ---------------------------------------------------------------------------
// K1 (r5..r11 verified GEMM core) + NEW: LDS transpose tail that emits the
// bf16 hT[c][n] slice directly (replaces K1b + the f32 h round-trip).
// Zero-init tail REMOVED (split-K partials now go to disjoint buffers).
// grid = 256 blocks x 32 rows.
// ---------------------------------------------------------------------------
__global__ __launch_bounds__(256) void k1_h(
    const float* __restrict__ x, const float* __restrict__ Wt,
    const float* __restrict__ bt, uint16_t* __restrict__ hT) {
  __shared__ float wtT[256 * 65];
  __shared__ float sbt[64];
  __shared__ uint16_t s_tr[64][34];   // [h-col][n-local 0..31], stride 68B
  const int t = threadIdx.x;
  const int lane = t & 63;
  const int w = t >> 6;

  for (int i = 0; i < 64; ++i)
    wtT[t * 65 + i] = Wt[(size_t)i * FF + t];
  if (t < 64) sbt[t] = bt[t];
  __syncthreads();

  const int n0 = blockIdx.x * 32;
  const int r0 = n0 + w * 8;
  const float binit = sbt[lane];
  float acc[8];
#pragma unroll
  for (int r = 0; r < 8; ++r) acc[r] = binit;

  for (int f4 = 0; f4 < FF; f4 += 4) {
    float4 xs[8];
#pragma unroll
    for (int r = 0; r < 8; ++r)
      xs[r] = *(const float4*)(x + (size_t)(r0 + r) * FF + f4);
    const float wt0 = wtT[(f4 + 0) * 65 + lane];
    const float wt1 = wtT[(f4 + 1) * 65 + lane];
    const float wt2 = wtT[(f4 + 2) * 65 + lane];
    const float wt3 = wtT[(f4 + 3) * 65 + lane];
#pragma unroll
    for (int r = 0; r < 8; ++r)
      acc[r] += xs[r].x * wt0 + xs[r].y * wt1 + xs[r].z * wt2 + xs[r].w * wt3;
  }

  // ---- NEW: in-block transpose, bf16 rounding identical to old K1b path ----
#pragma unroll
  for (int r = 0; r < 8; ++r)
    s_tr[lane][w * 8 + r] = f2bf(acc[r]);
  __syncthreads();
#pragma unroll
  for (int i = 0; i < 4; ++i) {
    int idx = i * 256 + t;          // 0..1023 dwords = 64 rows x 16 dwords
    int c = idx >> 4;               // h-column 0..63
    int d = idx & 15;               // dword within 32-wide n slice
    uint32_t v = (uint32_t)s_tr[c][2 * d] | ((uint32_t)s_tr[c][2 * d + 1] << 16);
    *(uint32_t*)(hT + (size_t)c * NN + n0 + 2 * d) = v;
  }
}

// ---------------------------------------------------------------------------
// K2: r8/r11 VERIFIED geometry (BM=16, 4 waves, block 256, split-K 2,
// grid 1024). CHANGED: (a) adj->bf16 via packed (lo|hi<<16)*0x3F80 --
// bit-identical output for adj in {0,1}, ~half the loop VALU; (b) degree
// accumulated packed 16+16; (c) partial sums STORED to disjoint
// nb_part[half] / deg_part[half] -- no global atomics, no pre-zeroing.
// ---------------------------------------------------------------------------
__global__ __launch_bounds__(256) void k2_attn(
    const int* __restrict__ adj, const uint16_t* __restrict__ hT,
    float* __restrict__ nb_part, int* __restrict__ deg_part) {
  __shared__ float s_part[4][16][64];   // 16 KB partial D
  __shared__ int   s_deg[16];

  const int t    = threadIdx.x;
  const int w    = t >> 6;
  const int lane = t & 63;
  const int m    = lane & 15;
  const int q    = lane >> 4;
  const int g    = blockIdx.x >> 1;
  const int half = blockIdx.x & 1;
  const int row0 = g * 16;

  if (t < 16) s_deg[t] = 0;
  __syncthreads();

  const int kbeg = half * (NN / 2) + w * (NN / 8);
  const int kend = kbeg + (NN / 8);

  f32x4 acc0 = 0, acc1 = 0, acc2 = 0, acc3 = 0;
  uint32_t degp = 0;                    // packed lo16/hi16 degree halves
  const int* __restrict__ arow = adj + (size_t)(row0 + m) * NN;
  const uint16_t* __restrict__ hrow = hT + (size_t)m * NN;

  for (int kb = kbeg; kb < kend; kb += 64) {
    const int k0 = kb + q * 8;        // chunk A octet
    const int k1 = k0 + 32;           // chunk B octet
    // ---- all loads first (r11-verified x2 unroll) ----
    int4 a0 = *(const int4*)(arow + k0);
    int4 a1 = *(const int4*)(arow + k0 + 4);
    int4 a2 = *(const int4*)(arow + k1);
    int4 a3 = *(const int4*)(arow + k1 + 4);
    bf16x8 b0 = *(const bf16x8*)(hrow + k0);
    bf16x8 b1 = *(const bf16x8*)(hrow + 16 * NN + k0);
    bf16x8 b2 = *(const bf16x8*)(hrow + 32 * NN + k0);
    bf16x8 b3 = *(const bf16x8*)(hrow + 48 * NN + k0);
    bf16x8 c0 = *(const bf16x8*)(hrow + k1);
    bf16x8 c1 = *(const bf16x8*)(hrow + 16 * NN + k1);
    bf16x8 c2 = *(const bf16x8*)(hrow + 32 * NN + k1);
    bf16x8 c3 = *(const bf16x8*)(hrow + 48 * NN + k1);
    // ---- packed adj pairs (adj values are {0,1} by construction) ----
    uint32_t p0 = (uint32_t)a0.x | ((uint32_t)a0.y << 16);
    uint32_t p1 = (uint32_t)a0.z | ((uint32_t)a0.w << 16);
    uint32_t p2 = (uint32_t)a1.x | ((uint32_t)a1.y << 16);
    uint32_t p3 = (uint32_t)a1.z | ((uint32_t)a1.w << 16);
    uint32_t p4 = (uint32_t)a2.x | ((uint32_t)a2.y << 16);
    uint32_t p5 = (uint32_t)a2.z | ((uint32_t)a2.w << 16);
    uint32_t p6 = (uint32_t)a3.x | ((uint32_t)a3.y << 16);
    uint32_t p7 = (uint32_t)a3.z | ((uint32_t)a3.w << 16);
    // bf16 pair word: (lo | hi<<16) * 0x3F80 == {lo?1.0bf:0, hi?1.0bf:0}
    union U { bf16x8 v; uint32_t u[4]; } afA, afB;
    afA.u[0] = p0 * 0x3F80u;
    afA.u[1] = p1 * 0x3F80u;
    afA.u[2] = p2 * 0x3F80u;
    afA.u[3] = p3 * 0x3F80u;
    afB.u[0] = p4 * 0x3F80u;
    afB.u[1] = p5 * 0x3F80u;
    afB.u[2] = p6 * 0x3F80u;
    afB.u[3] = p7 * 0x3F80u;
    degp += p0 + p1 + p2 + p3 + p4 + p5 + p6 + p7;  // halves <= 128, no carry
    // ---- 8 MFMAs (verbatim) ----
    acc0 = __builtin_amdgcn_mfma_f32_16x16x32_bf16(afA.v, b0, acc0, 0, 0, 0);
    acc1 = __builtin_amdgcn_mfma_f32_16x16x32_bf16(afA.v, b1, acc1, 0, 0, 0);
    acc2 = __builtin_amdgcn_mfma_f32_16x16x32_bf16(afA.v, b2, acc2, 0, 0, 0);
    acc3 = __builtin_amdgcn_mfma_f32_16x16x32_bf16(afA.v, b3, acc3, 0, 0, 0);
    acc0 = __builtin_amdgcn_mfma_f32_16x16x32_bf16(afB.v, c0, acc0, 0, 0, 0);
    acc1 = __builtin_amdgcn_mfma_f32_16x16x32_bf16(afB.v, c1, acc1, 0, 0, 0);
    acc2 = __builtin_amdgcn_mfma_f32_16x16x32_bf16(afB.v, c2, acc2, 0, 0, 0);
    acc3 = __builtin_amdgcn_mfma_f32_16x16x32_bf16(afB.v, c3, acc3, 0, 0, 0);
  }

  int degm = (int)(degp & 0xFFFFu) + (int)(degp >> 16);
  degm += __shfl_down(degm, 32, 64);
  degm += __shfl_down(degm, 16, 64);
  if (lane < 16) atomicAdd(&s_deg[lane], degm);   // LDS-scope only

#pragma unroll
  for (int rg = 0; rg < 4; ++rg) {
    s_part[w][q * 4 + rg][ 0 + m] = acc0[rg];
    s_part[w][q * 4 + rg][16 + m] = acc1[rg];
    s_part[w][q * 4 + rg][32 + m] = acc2[rg];
    s_part[w][q * 4 + rg][48 + m] = acc3[rg];
  }
  __syncthreads();

  // cross-wave reduce (r8 verbatim map) -> plain stores to this half's buffer
  float* __restrict__ dst = nb_part + ((size_t)half * NN + row0) * HH;
  for (int idx = t; idx < 16 * 64; idx += 256) {
    int r = idx >> 6, c = idx & 63;
    float s = s_part[0][r][c] + s_part[1][r][c] +
              s_part[2][r][c] + s_part[3][r][c];
    dst[(size_t)r * HH + c] = s;
  }
  if (t < 16) deg_part[half * NN + row0 + t] = s_deg[t];
}

// ---------------------------------------------------------------------------
// K3: epilogue, r4/r8-verified maps. CHANGED only in the s_nb formation:
// sums the two split-K partial buffers (deterministic order, no atomics).
// block = 256, 16 rows/block, grid = 512.
// ---------------------------------------------------------------------------
__global__ __launch_bounds__(256) void k3_epi(
    const float* __restrict__ x, const float* __restrict__ nb_part,
    const int* __restrict__ deg_part, const float* __restrict__ Wp,
    const float* __restrict__ bp, const float* __restrict__ gamma,
    const float* __restrict__ beta, float* __restrict__ out) {
  __shared__ float s_nb[16][64];
  __shared__ float s_y[16 * 256];

  const int t    = threadIdx.x;
  const int w    = t >> 6;
  const int lane = t & 63;
  const int row0 = blockIdx.x * 16;

  for (int idx = t; idx < 16 * 64; idx += 256) {
    int r = idx >> 6, c = idx & 63;
    int d = deg_part[row0 + r] + deg_part[NN + row0 + r];
    float s = nb_part[(size_t)(row0 + r) * HH + c] +
              nb_part[(size_t)(NN + row0 + r) * HH + c];
    s_nb[r][c] = (d > 0) ? s / (float)d : 0.f;
  }
  __syncthreads();

  // tf = neighbor @ Wp^T + bp ; y = x + tf   (r4-verified, r8 verbatim)
  {
    const int f = t;
    float wp[64];
    const float* wrow = Wp + (size_t)f * HH;
#pragma unroll
    for (int j = 0; j < 16; ++j) {
      float4 v = *(const float4*)(wrow + j * 4);
      wp[j * 4 + 0] = v.x; wp[j * 4 + 1] = v.y;
      wp[j * 4 + 2] = v.z; wp[j * 4 + 3] = v.w;
    }
    const float bpf = bp[f];
    for (int r = 0; r < 16; ++r) {
      float a = bpf;
#pragma unroll
      for (int k = 0; k < 64; k += 4) {
        float4 nv = *(const float4*)&s_nb[r][k];
        a += nv.x * wp[k] + nv.y * wp[k + 1] + nv.z * wp[k + 2] + nv.w * wp[k + 3];
      }
      float y = x[(size_t)(row0 + r) * FF + f] + a;
      s_y[r * 256 + f] = y;
    }
  }
  __syncthreads();

  // LayerNorm (r4-verified, r8 verbatim); wave w handles rows w*4 .. w*4+3
  for (int i = 0; i < 4; ++i) {
    const int r = w * 4 + i;
    float4 v = *(const float4*)&s_y[r * 256 + lane * 4];
    float sum = v.x + v.y + v.z + v.w;
    float ss  = v.x * v.x + v.y * v.y + v.z * v.z + v.w * v.w;
#pragma unroll
    for (int o = 32; o >= 1; o >>= 1) {
      sum += __shfl_xor(sum, o, 64);
      ss  += __shfl_xor(ss, o, 64);
    }
    const float mu  = sum * (1.0f / 256.0f);
    const float var = ss * (1.0f / 256.0f) - mu * mu;
    const float rs  = rsqrtf(var + 1e-5f);
    const int f0 = lane * 4;
    float4 g = *(const float4*)(gamma + f0);
    float4 b = *(const float4*)(beta + f0);
    float4 o4;
    o4.x = g.x * (v.x - mu) * rs + b.x;
    o4.y = g.y * (v.y - mu) * rs + b.y;
    o4.z = g.z * (v.z - mu) * rs + b.z;
    o4.w = g.w * (v.w - mu) * rs + b.w;
    *(float4*)(out + (size_t)(row0 + r) * FF + f0) = o4;
  }
}

extern "C" void kernel_launch(void* const* d_in, const int* in_sizes, int n_in,
                              void* d_out, int out_size, void* d_ws, size_t ws_size,
                              hipStream_t stream) {
  const float* x     = (const float*)d_in[0];
  const int*   adj   = (const int*)d_in[1];
  const float* Wt    = (const float*)d_in[2];
  const float* bt    = (const float*)d_in[3];
  // d_in[4] = Wa, d_in[5] = ba: provably dead (softmax scores are row-constant)
  const float* Wp    = (const float*)d_in[6];
  const float* bp    = (const float*)d_in[7];
  const float* gamma = (const float*)d_in[8];
  const float* beta  = (const float*)d_in[9];
  float* out = (float*)d_out;

  // ws layout: hT 1 MB | nb_part 4 MB (two split-K halves) | deg_part 64 KB
  uint16_t* hT       = (uint16_t*)d_ws;
  float*    nb_part  = (float*)((char*)d_ws + (1u << 20));
  int*      deg_part = (int*)((char*)d_ws + (5u << 20));

  k1_h  <<<256,  256, 0, stream>>>(x, Wt, bt, hT);
  k2_attn<<<1024, 256, 0, stream>>>(adj, hT, nb_part, deg_part);
  k3_epi <<<512,  256, 0, stream>>>(x, nb_part, deg_part, Wp, bp, gamma, beta, out);
}